// Round 1
// baseline (1352.147 us; speedup 1.0000x reference)
//
#include <hip/hip_runtime.h>
#include <math.h>

#define B 2
#define T 2048
#define C 1024
#define H 16
#define D 64
#define M (B*T)

// ---------------------------------------------------------------------------
// GEMM (NT): out[m,n] = sum_k A[m,k] * W[n,k]
// A: [M, C] row-major (K contiguous), W: [C_out=C, C] row-major (K contiguous)
// SCATTER=true: write to [B,H,T,D] layout (for Q/K/V); else [M,C] row-major.
// 64x64 tile, 256 threads, 4x4 micro-tile per thread, BK=16.
// ---------------------------------------------------------------------------
template<bool SCATTER>
__global__ __launch_bounds__(256)
void gemm_nt(const float* __restrict__ A, const float* __restrict__ W,
             float* __restrict__ out) {
    const int BM = 64, BN = 64, BK = 16;
    // +4 pad keeps rows 16B-aligned (stride 68 floats = 272B) and breaks
    // power-of-2 bank aliasing.
    __shared__ float As[BK][BM + 4];
    __shared__ float Bs[BK][BN + 4];

    const int t  = threadIdx.x;
    const int m0 = blockIdx.x * BM;
    const int n0 = blockIdx.y * BN;
    const int tm = (t >> 4) * 4;   // 16x16 thread grid
    const int tn = (t & 15) * 4;

    float acc[4][4] = {};

    for (int k0 = 0; k0 < C; k0 += BK) {
        // stage A tile (64x16) transposed into As[k][m]
        for (int i = t; i < BM * BK; i += 256) {
            int mm = i >> 4, kk = i & (BK - 1);
            As[kk][mm] = A[(size_t)(m0 + mm) * C + k0 + kk];
        }
        // stage W tile (64x16) transposed into Bs[k][n]
        for (int i = t; i < BN * BK; i += 256) {
            int nn = i >> 4, kk = i & (BK - 1);
            Bs[kk][nn] = W[(size_t)(n0 + nn) * C + k0 + kk];
        }
        __syncthreads();
        #pragma unroll
        for (int k = 0; k < BK; ++k) {
            float a[4], b[4];
            #pragma unroll
            for (int i = 0; i < 4; ++i) a[i] = As[k][tm + i];
            #pragma unroll
            for (int j = 0; j < 4; ++j) b[j] = Bs[k][tn + j];
            #pragma unroll
            for (int i = 0; i < 4; ++i)
                #pragma unroll
                for (int j = 0; j < 4; ++j)
                    acc[i][j] += a[i] * b[j];
        }
        __syncthreads();
    }

    #pragma unroll
    for (int i = 0; i < 4; ++i) {
        int m = m0 + tm + i;
        #pragma unroll
        for (int j = 0; j < 4; ++j) {
            int n = n0 + tn + j;
            if (SCATTER) {
                // m = b*T + t ; n = h*D + d  ->  [B,H,T,D]
                int bb = m >> 11;          // T = 2048
                int tt = m & (T - 1);
                int hh = n >> 6;           // D = 64
                int dd = n & (D - 1);
                out[(((size_t)bb * H + hh) * T + tt) * D + dd] = acc[i][j];
            } else {
                out[(size_t)m * C + n] = acc[i][j];
            }
        }
    }
}

// ---------------------------------------------------------------------------
// Causal flash attention. Q,K,V: [B,H,T,D] fp32. Y out: [B,T,C] fp32.
// One block per (q-block of 64 rows, b*h). 256 threads: 4 threads per q-row,
// each owns 16 columns (S) / 16 dims (O).
// ---------------------------------------------------------------------------
__global__ __launch_bounds__(256)
void attn_fwd(const float* __restrict__ Q, const float* __restrict__ K,
              const float* __restrict__ V, float* __restrict__ Y) {
    __shared__ float Qs[64][D + 4];   // [row][d]
    __shared__ float Kt[D][64 + 4];   // transposed: [d][key]
    __shared__ float Vs[64][D + 4];   // [key][d]
    __shared__ float Ps[64][64 + 4];  // [row][key]

    const int t  = threadIdx.x;
    const int qb = blockIdx.x;        // q-block index, 0..T/64-1
    const int bh = blockIdx.y;        // 0..B*H-1
    const int bb = bh / H, hh = bh % H;

    const float* Qb = Q + ((size_t)bh * T + (size_t)qb * 64) * D;
    const float* Kb = K + (size_t)bh * T * D;
    const float* Vb = V + (size_t)bh * T * D;

    const int r  = t >> 2;            // q-row within block, 0..63
    const int c0 = (t & 3) * 16;      // column/dim group base

    // stage Q block
    for (int i = t; i < 64 * D; i += 256)
        Qs[i / D][i % D] = Qb[i];

    float m = -INFINITY, l = 0.f;
    float o[16];
    #pragma unroll
    for (int j = 0; j < 16; ++j) o[j] = 0.f;

    for (int kb = 0; kb <= qb; ++kb) {
        __syncthreads();   // previous iter's LDS reads done (also covers Qs)
        for (int i = t; i < 64 * D; i += 256) {
            int row = i / D, d = i % D;
            float kv = Kb[(size_t)kb * 64 * D + i];
            Kt[d][row] = kv;
            Vs[row][d] = Vb[(size_t)kb * 64 * D + i];
        }
        __syncthreads();

        // S = (Q K^T) * scale for this thread's 16 columns
        float s[16];
        #pragma unroll
        for (int j = 0; j < 16; ++j) s[j] = 0.f;
        for (int d = 0; d < D; ++d) {
            float qv = Qs[r][d];
            #pragma unroll
            for (int j = 0; j < 16; ++j)
                s[j] += qv * Kt[d][c0 + j];
        }
        #pragma unroll
        for (int j = 0; j < 16; ++j) s[j] *= 0.125f;  // 1/sqrt(64)

        if (kb == qb) {   // diagonal block: mask key > query
            #pragma unroll
            for (int j = 0; j < 16; ++j)
                if (c0 + j > r) s[j] = -INFINITY;
        }

        // row max across the 4-thread group
        float mloc = s[0];
        #pragma unroll
        for (int j = 1; j < 16; ++j) mloc = fmaxf(mloc, s[j]);
        mloc = fmaxf(mloc, __shfl_xor(mloc, 1));
        mloc = fmaxf(mloc, __shfl_xor(mloc, 2));
        float newm = fmaxf(m, mloc);
        float alpha = __expf(m - newm);

        float p[16], lloc = 0.f;
        #pragma unroll
        for (int j = 0; j < 16; ++j) { p[j] = __expf(s[j] - newm); lloc += p[j]; }
        lloc += __shfl_xor(lloc, 1);
        lloc += __shfl_xor(lloc, 2);
        l = l * alpha + lloc;
        m = newm;

        #pragma unroll
        for (int j = 0; j < 16; ++j) o[j] *= alpha;

        #pragma unroll
        for (int j = 0; j < 16; ++j) Ps[r][c0 + j] = p[j];
        __syncthreads();

        // O += P @ V  (this thread: row r, dims c0..c0+15)
        for (int k = 0; k < 64; ++k) {
            float pv = Ps[r][k];
            #pragma unroll
            for (int j = 0; j < 16; ++j)
                o[j] += pv * Vs[k][c0 + j];
        }
    }

    const float inv = 1.f / l;
    const int q = qb * 64 + r;
    float* yp = Y + ((size_t)bb * T + q) * C + hh * D + c0;
    #pragma unroll
    for (int j = 0; j < 16; ++j) yp[j] = o[j] * inv;
}

// ---------------------------------------------------------------------------
extern "C" void kernel_launch(void* const* d_in, const int* in_sizes, int n_in,
                              void* d_out, int out_size, void* d_ws, size_t ws_size,
                              hipStream_t stream) {
    const float* x  = (const float*)d_in[0];
    const float* Wq = (const float*)d_in[1];
    const float* Wk = (const float*)d_in[2];
    const float* Wv = (const float*)d_in[3];
    const float* Wo = (const float*)d_in[4];
    float* out = (float*)d_out;

    const size_t per = (size_t)B * H * T * D;  // 4M elements = 16 MB
    float* Qw = (float*)d_ws;
    float* Kw = Qw + per;
    float* Vw = Kw + per;
    float* Yw = Vw + per;   // attention output in [B,T,C] layout

    dim3 blk(256);
    dim3 gg(M / 64, C / 64);
    gemm_nt<true><<<gg, blk, 0, stream>>>(x, Wq, Qw);
    gemm_nt<true><<<gg, blk, 0, stream>>>(x, Wk, Kw);
    gemm_nt<true><<<gg, blk, 0, stream>>>(x, Wv, Vw);

    dim3 ga(T / 64, B * H);
    attn_fwd<<<ga, blk, 0, stream>>>(Qw, Kw, Vw, Yw);

    gemm_nt<false><<<gg, blk, 0, stream>>>(Yw, Wo, out);
}

// Round 2
// 219.956 us; speedup vs baseline: 6.1474x; 6.1474x over previous
//
#include <hip/hip_runtime.h>
#include <math.h>

typedef short bf16x8 __attribute__((ext_vector_type(8)));
typedef float f32x4 __attribute__((ext_vector_type(4)));

constexpr int Bc = 2, Tc = 2048, Cc = 1024, Hc = 16, Dc = 64;
constexpr int Mc = Bc * Tc;  // 4096

__device__ __forceinline__ unsigned short f2bf(float f) {
    union { float f; unsigned u; } v; v.f = f;
    unsigned r = v.u + 0x7fffu + ((v.u >> 16) & 1u);  // RNE
    return (unsigned short)(r >> 16);
}

__device__ __forceinline__ void gload16(const void* g, void* l) {
    __builtin_amdgcn_global_load_lds(
        (const __attribute__((address_space(1))) void*)g,
        (__attribute__((address_space(3))) void*)l, 16, 0, 0);
}

// ---------------------------------------------------------------------------
__global__ __launch_bounds__(256)
void cast_bf16(const float* __restrict__ in, unsigned short* __restrict__ out, int n8) {
    int i = blockIdx.x * 256 + threadIdx.x;
    if (i >= n8) return;
    const float4* p = (const float4*)in;
    float4 a = p[i * 2], b = p[i * 2 + 1];
    union { unsigned short u[8]; bf16x8 v; } r;
    r.u[0] = f2bf(a.x); r.u[1] = f2bf(a.y); r.u[2] = f2bf(a.z); r.u[3] = f2bf(a.w);
    r.u[4] = f2bf(b.x); r.u[5] = f2bf(b.y); r.u[6] = f2bf(b.z); r.u[7] = f2bf(b.w);
    *(bf16x8*)(out + i * 8) = r.v;
}

// ---------------------------------------------------------------------------
// NT GEMM, bf16 MFMA, m97 structure: 128x128 tile, BK=32, 4 waves (2x2),
// global_load_lds(16B) staging, 16 MFMA/K-step/wave.
// A[M,1024] row-major, W[1024,1024] row-major (both K-contiguous).
// MODE 0: scatter bf16 [B,H,T,D]; 1: scatter bf16 [B,H,D,T] (V^T);
// MODE 2: bf16 [M,N]; 3: fp32 [M,N].
// ---------------------------------------------------------------------------
template<int MODE>
__global__ __launch_bounds__(256)
void gemm_bt(const unsigned short* __restrict__ A,
             const unsigned short* __restrict__ W,
             void* __restrict__ outp) {
    __shared__ unsigned short As[128 * 32];
    __shared__ unsigned short Bs[128 * 32];
    const int t = threadIdx.x;
    const int lane = t & 63, l15 = lane & 15, l4 = lane >> 4;
    const int w = t >> 6, wr = w >> 1, wc = w & 1;
    const int m0 = blockIdx.x * 128, n0 = blockIdx.y * 128;

    f32x4 acc[4][4] = {};

    for (int k0 = 0; k0 < Cc; k0 += 32) {
        __syncthreads();
        #pragma unroll
        for (int it = 0; it < 2; ++it) {
            int c = t + it * 256;
            int row = c >> 2, ko = (c & 3) << 3;
            gload16(A + (size_t)(m0 + row) * Cc + k0 + ko, As + c * 8);
            gload16(W + (size_t)(n0 + row) * Cc + k0 + ko, Bs + c * 8);
        }
        __syncthreads();
        bf16x8 af[4], bfr[4];
        #pragma unroll
        for (int i = 0; i < 4; ++i)
            af[i] = *(const bf16x8*)(As + ((wr * 64 + i * 16 + l15) * 32 + l4 * 8));
        #pragma unroll
        for (int j = 0; j < 4; ++j)
            bfr[j] = *(const bf16x8*)(Bs + ((wc * 64 + j * 16 + l15) * 32 + l4 * 8));
        #pragma unroll
        for (int i = 0; i < 4; ++i)
            #pragma unroll
            for (int j = 0; j < 4; ++j)
                acc[i][j] = __builtin_amdgcn_mfma_f32_16x16x32_bf16(af[i], bfr[j], acc[i][j], 0, 0, 0);
    }

    const int r0 = wr * 64 + (l4 << 2);
    const int c0 = wc * 64 + l15;
    #pragma unroll
    for (int i = 0; i < 4; ++i)
        #pragma unroll
        for (int j = 0; j < 4; ++j)
            #pragma unroll
            for (int r = 0; r < 4; ++r) {
                int row = m0 + r0 + i * 16 + r;
                int col = n0 + c0 + j * 16;
                float v = acc[i][j][r];
                if (MODE == 0) {
                    int bb = row >> 11, tt = row & (Tc - 1);
                    int hh = col >> 6, dd = col & 63;
                    ((unsigned short*)outp)[((((size_t)bb * Hc + hh) * Tc + tt) << 6) + dd] = f2bf(v);
                } else if (MODE == 1) {
                    int bb = row >> 11, tt = row & (Tc - 1);
                    int hh = col >> 6, dd = col & 63;
                    ((unsigned short*)outp)[(((size_t)bb * Hc + hh) * Dc + dd) * Tc + tt] = f2bf(v);
                } else if (MODE == 2) {
                    ((unsigned short*)outp)[(size_t)row * Cc + col] = f2bf(v);
                } else {
                    ((float*)outp)[(size_t)row * Cc + col] = v;
                }
            }
}

// ---------------------------------------------------------------------------
// MFMA causal flash attention.
// Q,K bf16 [B,H,T,64]; Vt bf16 [B,H,64,T]; Y bf16 [B,T,C].
// Block: 128 q-rows x one (b,h); 4 waves x 32 rows. KVBLK=64.
// K/Vt tiles in LDS, XOR-swizzled (rows are 128B -> G4 conflict case):
// pre-swizzled global source + swizzled reads (same involution).
// ---------------------------------------------------------------------------
__global__ __launch_bounds__(256)
void attn_mfma(const unsigned short* __restrict__ Q,
               const unsigned short* __restrict__ K,
               const unsigned short* __restrict__ Vt,
               unsigned short* __restrict__ Y) {
    __shared__ unsigned short Ks[64 * 64];     // [key][d]
    __shared__ unsigned short Vs[64 * 64];     // [d][key]
    __shared__ unsigned short Ps[4][32 * 64];  // per-wave P [q][key]

    const int t = threadIdx.x, lane = t & 63, w = t >> 6;
    const int l15 = lane & 15, l4 = lane >> 4;
    const int qb = blockIdx.x, bh = blockIdx.y;
    const int bb = bh >> 4, hh = bh & 15;
    const int qbase = qb * 128 + w * 32;

    const unsigned short* Qp = Q + (size_t)bh * Tc * Dc;
    const unsigned short* Kp = K + (size_t)bh * Tc * Dc;
    const unsigned short* Vp = Vt + (size_t)bh * Dc * Tc;

    // Q fragments in registers: [i][kc], A-layout of 16x16x32
    bf16x8 qf[2][2];
    #pragma unroll
    for (int i = 0; i < 2; ++i)
        #pragma unroll
        for (int kc = 0; kc < 2; ++kc)
            qf[i][kc] = *(const bf16x8*)(Qp + (size_t)(qbase + i * 16 + l15) * 64 + kc * 32 + l4 * 8);

    f32x4 o[2][4] = {};
    float mr[2][4], lr[2][4];
    #pragma unroll
    for (int i = 0; i < 2; ++i)
        #pragma unroll
        for (int r = 0; r < 4; ++r) { mr[i][r] = -INFINITY; lr[i][r] = 0.f; }

    const int nkb = 2 * qb + 2;
    for (int kb = 0; kb < nkb; ++kb) {
        __syncthreads();
        #pragma unroll
        for (int it = 0; it < 2; ++it) {
            int c = t + it * 256;
            int row = c >> 3, slot = c & 7;
            int ss = slot ^ (row & 7);  // pre-swizzled source
            gload16(Kp + (size_t)(kb * 64 + row) * 64 + ss * 8, Ks + c * 8);
            gload16(Vp + (size_t)row * Tc + kb * 64 + ss * 8, Vs + c * 8);
        }
        __syncthreads();

        if (kb * 64 > qbase + 31) continue;  // all keys > all rows (barriers already done)
        const bool need_mask = (kb * 64 + 63) > qbase;

        // K fragments (B-layout): col=key=n*16+l15, k=d
        bf16x8 kf[4][2];
        #pragma unroll
        for (int n = 0; n < 4; ++n)
            #pragma unroll
            for (int kc = 0; kc < 2; ++kc) {
                int key = n * 16 + l15;
                int boff = (kc * 64 + l4 * 16) ^ ((key & 7) << 4);
                kf[n][kc] = *(const bf16x8*)(Ks + (((key << 7) + boff) >> 1));
            }

        unsigned short* Pw = Ps[w];
        #pragma unroll
        for (int i = 0; i < 2; ++i) {
            f32x4 s[4] = {};
            #pragma unroll
            for (int kc = 0; kc < 2; ++kc)
                #pragma unroll
                for (int n = 0; n < 4; ++n)
                    s[n] = __builtin_amdgcn_mfma_f32_16x16x32_bf16(qf[i][kc], kf[n][kc], s[n], 0, 0, 0);

            #pragma unroll
            for (int n = 0; n < 4; ++n)
                #pragma unroll
                for (int r = 0; r < 4; ++r) s[n][r] *= 0.125f;

            if (need_mask) {
                #pragma unroll
                for (int n = 0; n < 4; ++n) {
                    int key = kb * 64 + n * 16 + l15;
                    int qrow = qbase + i * 16 + (l4 << 2);
                    #pragma unroll
                    for (int r = 0; r < 4; ++r)
                        if (key > qrow + r) s[n][r] = -1e30f;
                }
            }

            // online softmax: rows live in (reg r) x (lane>>4 group); reduce over lanes 0..15
            float al[4];
            #pragma unroll
            for (int r = 0; r < 4; ++r) {
                float mx = fmaxf(fmaxf(s[0][r], s[1][r]), fmaxf(s[2][r], s[3][r]));
                mx = fmaxf(mx, __shfl_xor(mx, 1));
                mx = fmaxf(mx, __shfl_xor(mx, 2));
                mx = fmaxf(mx, __shfl_xor(mx, 4));
                mx = fmaxf(mx, __shfl_xor(mx, 8));
                float mn = fmaxf(mr[i][r], mx);
                al[r] = __expf(mr[i][r] - mn);
                mr[i][r] = mn;
            }
            float ls[4] = {0.f, 0.f, 0.f, 0.f};
            #pragma unroll
            for (int n = 0; n < 4; ++n)
                #pragma unroll
                for (int r = 0; r < 4; ++r) {
                    float p = __expf(s[n][r] - mr[i][r]);
                    s[n][r] = p;
                    ls[r] += p;
                }
            #pragma unroll
            for (int r = 0; r < 4; ++r) {
                float l2 = ls[r];
                l2 += __shfl_xor(l2, 1);
                l2 += __shfl_xor(l2, 2);
                l2 += __shfl_xor(l2, 4);
                l2 += __shfl_xor(l2, 8);
                lr[i][r] = lr[i][r] * al[r] + l2;
            }
            #pragma unroll
            for (int nd = 0; nd < 4; ++nd)
                #pragma unroll
                for (int r = 0; r < 4; ++r)
                    o[i][nd][r] *= al[r];

            // P -> per-wave LDS (bf16, swizzled), then PV
            #pragma unroll
            for (int n = 0; n < 4; ++n) {
                int col2 = (n * 16 + l15) * 2;
                #pragma unroll
                for (int r = 0; r < 4; ++r) {
                    int row = i * 16 + (l4 << 2) + r;
                    Pw[((row << 7) + (col2 ^ ((row & 7) << 4))) >> 1] = f2bf(s[n][r]);
                }
            }
            #pragma unroll
            for (int kc = 0; kc < 2; ++kc) {
                int prow = i * 16 + l15;
                int pboff = (kc * 64 + l4 * 16) ^ ((prow & 7) << 4);
                bf16x8 pf = *(const bf16x8*)(Pw + (((prow << 7) + pboff) >> 1));
                #pragma unroll
                for (int nd = 0; nd < 4; ++nd) {
                    int d = nd * 16 + l15;
                    int vboff = (kc * 64 + l4 * 16) ^ ((d & 7) << 4);
                    bf16x8 vf = *(const bf16x8*)(Vs + (((d << 7) + vboff) >> 1));
                    o[i][nd] = __builtin_amdgcn_mfma_f32_16x16x32_bf16(pf, vf, o[i][nd], 0, 0, 0);
                }
            }
        }
    }

    #pragma unroll
    for (int i = 0; i < 2; ++i)
        #pragma unroll
        for (int r = 0; r < 4; ++r) {
            int q = qbase + i * 16 + (l4 << 2) + r;
            float inv = 1.f / lr[i][r];
            size_t base = ((size_t)bb * Tc + q) * Cc + hh * 64;
            #pragma unroll
            for (int nd = 0; nd < 4; ++nd)
                Y[base + nd * 16 + l15] = f2bf(o[i][nd][r] * inv);
        }
}

// ---------------------------------------------------------------------------
extern "C" void kernel_launch(void* const* d_in, const int* in_sizes, int n_in,
                              void* d_out, int out_size, void* d_ws, size_t ws_size,
                              hipStream_t stream) {
    const float* x  = (const float*)d_in[0];
    const float* Wq = (const float*)d_in[1];
    const float* Wk = (const float*)d_in[2];
    const float* Wv = (const float*)d_in[3];
    const float* Wo = (const float*)d_in[4];

    unsigned short* ws = (unsigned short*)d_ws;
    const size_t nX = (size_t)Mc * Cc;   // 4194304
    const size_t nW = (size_t)Cc * Cc;   // 1048576
    size_t off = 0;
    unsigned short* xb  = ws + off; off += nX;
    unsigned short* Wqb = ws + off; off += nW;
    unsigned short* Wkb = ws + off; off += nW;
    unsigned short* Wvb = ws + off; off += nW;
    unsigned short* Wob = ws + off; off += nW;
    unsigned short* Qw  = ws + off; off += nX;
    unsigned short* Kw  = ws + off; off += nX;
    unsigned short* Vtw = ws + off; off += nX;
    unsigned short* Yb  = ws + off; off += nX;  // total ~50.3 MB

    dim3 blk(256);
    cast_bf16<<<dim3((int)(nX / 8 / 256)), blk, 0, stream>>>(x,  xb,  (int)(nX / 8));
    cast_bf16<<<dim3((int)(nW / 8 / 256)), blk, 0, stream>>>(Wq, Wqb, (int)(nW / 8));
    cast_bf16<<<dim3((int)(nW / 8 / 256)), blk, 0, stream>>>(Wk, Wkb, (int)(nW / 8));
    cast_bf16<<<dim3((int)(nW / 8 / 256)), blk, 0, stream>>>(Wv, Wvb, (int)(nW / 8));
    cast_bf16<<<dim3((int)(nW / 8 / 256)), blk, 0, stream>>>(Wo, Wob, (int)(nW / 8));

    dim3 gg(Mc / 128, Cc / 128);  // 32 x 8
    gemm_bt<0><<<gg, blk, 0, stream>>>(xb, Wqb, Qw);
    gemm_bt<0><<<gg, blk, 0, stream>>>(xb, Wkb, Kw);
    gemm_bt<1><<<gg, blk, 0, stream>>>(xb, Wvb, Vtw);

    dim3 ga(Tc / 128, Bc * Hc);   // 16 x 32
    attn_mfma<<<ga, blk, 0, stream>>>(Qw, Kw, Vtw, Yb);

    gemm_bt<3><<<gg, blk, 0, stream>>>(Yb, Wob, d_out);
}

// Round 3
// 171.957 us; speedup vs baseline: 7.8633x; 1.2791x over previous
//
#include <hip/hip_runtime.h>
#include <math.h>

typedef short bf16x8 __attribute__((ext_vector_type(8)));
typedef float f32x4 __attribute__((ext_vector_type(4)));
typedef float f32x16 __attribute__((ext_vector_type(16)));
typedef int int2v __attribute__((ext_vector_type(2)));

constexpr int Bc = 2, Tc = 2048, Cc = 1024, Hc = 16, Dc = 64;
constexpr int Mc = Bc * Tc;  // 4096

__device__ __forceinline__ unsigned short f2bf(float f) {
    union { float f; unsigned u; } v; v.f = f;
    unsigned r = v.u + 0x7fffu + ((v.u >> 16) & 1u);  // RNE
    return (unsigned short)(r >> 16);
}

__device__ __forceinline__ unsigned cvt_pk_bf16(float lo, float hi) {
    unsigned r;
    asm("v_cvt_pk_bf16_f32 %0, %1, %2" : "=v"(r) : "v"(lo), "v"(hi));
    return r;
}

__device__ __forceinline__ void gload16(const void* g, void* l) {
    __builtin_amdgcn_global_load_lds(
        (const __attribute__((address_space(1))) void*)g,
        (__attribute__((address_space(3))) void*)l, 16, 0, 0);
}

// ---------------------------------------------------------------------------
__global__ __launch_bounds__(256)
void cast_bf16(const float* __restrict__ in, unsigned short* __restrict__ out, int n8) {
    int i = blockIdx.x * 256 + threadIdx.x;
    if (i >= n8) return;
    const float4* p = (const float4*)in;
    float4 a = p[i * 2], b = p[i * 2 + 1];
    union { unsigned short u[8]; bf16x8 v; } r;
    r.u[0] = f2bf(a.x); r.u[1] = f2bf(a.y); r.u[2] = f2bf(a.z); r.u[3] = f2bf(a.w);
    r.u[4] = f2bf(b.x); r.u[5] = f2bf(b.y); r.u[6] = f2bf(b.z); r.u[7] = f2bf(b.w);
    *(bf16x8*)(out + i * 8) = r.v;
}

// all 4 weights in one launch (1024x1024 each, n8 = 131072, grid.x = 512, grid.y = 4)
__global__ __launch_bounds__(256)
void cast_w4(const float* __restrict__ a, const float* __restrict__ b,
             const float* __restrict__ c, const float* __restrict__ d,
             unsigned short* __restrict__ oa, unsigned short* __restrict__ ob,
             unsigned short* __restrict__ oc, unsigned short* __restrict__ od) {
    const float* src = blockIdx.y == 0 ? a : blockIdx.y == 1 ? b : blockIdx.y == 2 ? c : d;
    unsigned short* dst = blockIdx.y == 0 ? oa : blockIdx.y == 1 ? ob : blockIdx.y == 2 ? oc : od;
    int i = blockIdx.x * 256 + threadIdx.x;
    const float4* p = (const float4*)src;
    float4 x = p[i * 2], y = p[i * 2 + 1];
    union { unsigned short u[8]; bf16x8 v; } r;
    r.u[0] = f2bf(x.x); r.u[1] = f2bf(x.y); r.u[2] = f2bf(x.z); r.u[3] = f2bf(x.w);
    r.u[4] = f2bf(y.x); r.u[5] = f2bf(y.y); r.u[6] = f2bf(y.z); r.u[7] = f2bf(y.w);
    *(bf16x8*)(dst + i * 8) = r.v;
}

// ---------------------------------------------------------------------------
// NT GEMM, bf16 MFMA, m97 structure: 128x128 tile, BK=32, 4 waves (2x2),
// global_load_lds(16B) staging, 16 MFMA/K-step/wave.
// MODE 0: scatter bf16 [B,H,T,D]; 1: scatter bf16 [B,H,D,T] (V^T);
// MODE 2: bf16 [M,N]; 3: fp32 [M,N].
// ---------------------------------------------------------------------------
template<int MODE>
__global__ __launch_bounds__(256)
void gemm_bt(const unsigned short* __restrict__ A,
             const unsigned short* __restrict__ W,
             void* __restrict__ outp) {
    __shared__ unsigned short As[128 * 32];
    __shared__ unsigned short Bs[128 * 32];
    const int t = threadIdx.x;
    const int lane = t & 63, l15 = lane & 15, l4 = lane >> 4;
    const int w = t >> 6, wr = w >> 1, wc = w & 1;
    const int m0 = blockIdx.x * 128, n0 = blockIdx.y * 128;

    f32x4 acc[4][4] = {};

    for (int k0 = 0; k0 < Cc; k0 += 32) {
        __syncthreads();
        #pragma unroll
        for (int it = 0; it < 2; ++it) {
            int c = t + it * 256;
            int row = c >> 2, ko = (c & 3) << 3;
            gload16(A + (size_t)(m0 + row) * Cc + k0 + ko, As + c * 8);
            gload16(W + (size_t)(n0 + row) * Cc + k0 + ko, Bs + c * 8);
        }
        __syncthreads();
        bf16x8 af[4], bfr[4];
        #pragma unroll
        for (int i = 0; i < 4; ++i)
            af[i] = *(const bf16x8*)(As + ((wr * 64 + i * 16 + l15) * 32 + l4 * 8));
        #pragma unroll
        for (int j = 0; j < 4; ++j)
            bfr[j] = *(const bf16x8*)(Bs + ((wc * 64 + j * 16 + l15) * 32 + l4 * 8));
        #pragma unroll
        for (int i = 0; i < 4; ++i)
            #pragma unroll
            for (int j = 0; j < 4; ++j)
                acc[i][j] = __builtin_amdgcn_mfma_f32_16x16x32_bf16(af[i], bfr[j], acc[i][j], 0, 0, 0);
    }

    const int r0 = wr * 64 + (l4 << 2);
    const int c0 = wc * 64 + l15;
    #pragma unroll
    for (int i = 0; i < 4; ++i)
        #pragma unroll
        for (int j = 0; j < 4; ++j)
            #pragma unroll
            for (int r = 0; r < 4; ++r) {
                int row = m0 + r0 + i * 16 + r;
                int col = n0 + c0 + j * 16;
                float v = acc[i][j][r];
                if (MODE == 0) {
                    int bb = row >> 11, tt = row & (Tc - 1);
                    int hh = col >> 6, dd = col & 63;
                    ((unsigned short*)outp)[((((size_t)bb * Hc + hh) * Tc + tt) << 6) + dd] = f2bf(v);
                } else if (MODE == 1) {
                    int bb = row >> 11, tt = row & (Tc - 1);
                    int hh = col >> 6, dd = col & 63;
                    ((unsigned short*)outp)[(((size_t)bb * Hc + hh) * Dc + dd) * Tc + tt] = f2bf(v);
                } else if (MODE == 2) {
                    ((unsigned short*)outp)[(size_t)row * Cc + col] = f2bf(v);
                } else {
                    ((float*)outp)[(size_t)row * Cc + col] = v;
                }
            }
}

// ---------------------------------------------------------------------------
// MFMA causal flash attention, swapped-operand 32x32x16 structure.
// Q,K bf16 [B,H,T,64]; Vt bf16 [B,H,64,T]; Y bf16 [B,T,C].
// Block: 128 q-rows x one (b,h); 4 waves x 32 q-rows. KVBLK=64.
// S^T = mfma(K, Q): lane owns q=lane&31, keys in regs -> lane-local softmax.
// O^T = mfma(V^T, P^T): rescale is lane-local; P^T built in-register via
// v_cvt_pk_bf16_f32 + permlane32_swap (T12). K/V LDS double-buffered,
// XOR-swizzled (pre-swizzled global source + swizzled reads, rule #21).
// ---------------------------------------------------------------------------
__global__ __launch_bounds__(256)
void attn_mfma(const unsigned short* __restrict__ Q,
               const unsigned short* __restrict__ K,
               const unsigned short* __restrict__ Vt,
               unsigned short* __restrict__ Y) {
    __shared__ unsigned short Ks[2][64 * 64];  // [buf][key][d]   (swizzled)
    __shared__ unsigned short Vs[2][64 * 64];  // [buf][d][key]   (swizzled)

    const int t = threadIdx.x, lane = t & 63, w = t >> 6;
    const int l31 = lane & 31, h = lane >> 5;
    const int qb = blockIdx.x, bh = blockIdx.y;
    const int bb = bh >> 4, hh = bh & 15;
    const int qbase = qb * 128 + w * 32;
    const int q = qbase + l31;

    const unsigned short* Qp = Q + (size_t)bh * Tc * Dc;
    const unsigned short* Kp = K + (size_t)bh * Tc * Dc;
    const unsigned short* Vp = Vt + (size_t)bh * Dc * Tc;

    // Q as B-operand: col=q=lane&31, k = kc*16 + h*8 + j
    bf16x8 qf[4];
    #pragma unroll
    for (int kc = 0; kc < 4; ++kc)
        qf[kc] = *(const bf16x8*)(Qp + (size_t)q * 64 + kc * 16 + h * 8);

    f32x16 ot[2] = {};          // O^T: [dt] rows d=dt*32+(r&3)+8*(r>>2)+4h, col q
    float m = -INFINITY, lsum = 0.f;

    auto stage = [&](int kb, int buf) {
        #pragma unroll
        for (int it = 0; it < 2; ++it) {
            int c = t + it * 256;
            int row = c >> 3, slot = c & 7;
            int ss = slot ^ (row & 7);  // pre-swizzled source
            gload16(Kp + (size_t)(kb * 64 + row) * 64 + ss * 8, &Ks[buf][c * 8]);
            gload16(Vp + (size_t)row * Tc + kb * 64 + ss * 8, &Vs[buf][c * 8]);
        }
    };

    const int nkb = 2 * qb + 2;
    stage(0, 0);
    __syncthreads();

    for (int kb = 0; kb < nkb; ++kb) {
        const int cur = kb & 1;
        if (kb + 1 < nkb) stage(kb + 1, cur ^ 1);  // prefetch overlaps compute

        if (kb * 64 <= qbase + 31) {
            // ---- S^T = K @ Q^T  (2 key-tiles of 32) ----
            f32x16 st[2] = {};
            #pragma unroll
            for (int nt = 0; nt < 2; ++nt) {
                int key = nt * 32 + l31;
                #pragma unroll
                for (int kc = 0; kc < 4; ++kc) {
                    int boff = (kc * 32 + h * 16) ^ ((key & 7) << 4);
                    bf16x8 kf = *(const bf16x8*)(&Ks[cur][((key << 7) + boff) >> 1]);
                    st[nt] = __builtin_amdgcn_mfma_f32_32x32x16_bf16(kf, qf[kc], st[nt], 0, 0, 0);
                }
            }
            #pragma unroll
            for (int nt = 0; nt < 2; ++nt)
                #pragma unroll
                for (int r = 0; r < 16; ++r) st[nt][r] *= 0.125f;

            if (kb * 64 + 63 > qbase) {  // causal mask needed
                #pragma unroll
                for (int nt = 0; nt < 2; ++nt)
                    #pragma unroll
                    for (int r = 0; r < 16; ++r) {
                        int key = kb * 64 + nt * 32 + (r & 3) + 8 * (r >> 2) + 4 * h;
                        if (key > q) st[nt][r] = -1e30f;
                    }
            }

            // ---- lane-local softmax (tree max + one cross-half shuffle) ----
            float mx[16];
            #pragma unroll
            for (int r = 0; r < 16; ++r) mx[r] = fmaxf(st[0][r], st[1][r]);
            #pragma unroll
            for (int s2 = 8; s2 > 0; s2 >>= 1)
                #pragma unroll
                for (int r = 0; r < s2; ++r) mx[r] = fmaxf(mx[r], mx[r + s2]);
            float tmax = fmaxf(mx[0], __shfl_xor(mx[0], 32));
            float mn = fmaxf(m, tmax);
            float al = __expf(m - mn);
            m = mn;

            float ps = 0.f;
            #pragma unroll
            for (int nt = 0; nt < 2; ++nt)
                #pragma unroll
                for (int r = 0; r < 16; ++r) {
                    float p = __expf(st[nt][r] - m);
                    st[nt][r] = p;
                    ps += p;
                }
            lsum = lsum * al + ps;  // per-half partial; reduced once at end
            #pragma unroll
            for (int dt = 0; dt < 2; ++dt)
                #pragma unroll
                for (int r = 0; r < 16; ++r) ot[dt][r] *= al;

            // ---- P^T -> bf16 B-frags in-register, then PV ----
            #pragma unroll
            for (int nt = 0; nt < 2; ++nt) {
                // k-step sIdx=0 (key offs 0..15 of this tile): regs 0..7
                unsigned a0 = cvt_pk_bf16(st[nt][0],  st[nt][1]);
                unsigned b0 = cvt_pk_bf16(st[nt][4],  st[nt][5]);
                unsigned a1 = cvt_pk_bf16(st[nt][2],  st[nt][3]);
                unsigned b1 = cvt_pk_bf16(st[nt][6],  st[nt][7]);
                int2v r0 = __builtin_amdgcn_permlane32_swap((int)a0, (int)b0, false, false);
                int2v r1 = __builtin_amdgcn_permlane32_swap((int)a1, (int)b1, false, false);
                union { unsigned u[4]; bf16x8 v; } pf0, pf1;
                pf0.u[0] = r0.x; pf0.u[1] = r1.x; pf0.u[2] = r0.y; pf0.u[3] = r1.y;
                // k-step sIdx=1 (key offs 16..31): regs 8..15
                unsigned c0 = cvt_pk_bf16(st[nt][8],  st[nt][9]);
                unsigned d0 = cvt_pk_bf16(st[nt][12], st[nt][13]);
                unsigned c1 = cvt_pk_bf16(st[nt][10], st[nt][11]);
                unsigned d1 = cvt_pk_bf16(st[nt][14], st[nt][15]);
                int2v r2 = __builtin_amdgcn_permlane32_swap((int)c0, (int)d0, false, false);
                int2v r3 = __builtin_amdgcn_permlane32_swap((int)c1, (int)d1, false, false);
                pf1.u[0] = r2.x; pf1.u[1] = r3.x; pf1.u[2] = r2.y; pf1.u[3] = r3.y;

                #pragma unroll
                for (int dt = 0; dt < 2; ++dt) {
                    int d = dt * 32 + l31;
                    int v0off = (nt * 64 + h * 16) ^ ((d & 7) << 4);
                    bf16x8 vf0 = *(const bf16x8*)(&Vs[cur][((d << 7) + v0off) >> 1]);
                    ot[dt] = __builtin_amdgcn_mfma_f32_32x32x16_bf16(vf0, pf0.v, ot[dt], 0, 0, 0);
                }
                #pragma unroll
                for (int dt = 0; dt < 2; ++dt) {
                    int d = dt * 32 + l31;
                    int v1off = (nt * 64 + 32 + h * 16) ^ ((d & 7) << 4);
                    bf16x8 vf1 = *(const bf16x8*)(&Vs[cur][((d << 7) + v1off) >> 1]);
                    ot[dt] = __builtin_amdgcn_mfma_f32_32x32x16_bf16(vf1, pf1.v, ot[dt], 0, 0, 0);
                }
            }
        }
        __syncthreads();  // drains prefetch (vmcnt0) + publishes buffers
    }

    // ---- epilogue: cross-half l reduce, normalize, scattered 8B stores ----
    float lf = lsum + __shfl_xor(lsum, 32);
    float inv = 1.f / lf;
    size_t base = ((size_t)bb * Tc + q) * Cc + hh * 64;
    #pragma unroll
    for (int dt = 0; dt < 2; ++dt)
        #pragma unroll
        for (int rg = 0; rg < 4; ++rg) {
            int d0 = dt * 32 + rg * 8 + 4 * h;
            ushort4 s4;
            s4.x = f2bf(ot[dt][rg * 4 + 0] * inv);
            s4.y = f2bf(ot[dt][rg * 4 + 1] * inv);
            s4.z = f2bf(ot[dt][rg * 4 + 2] * inv);
            s4.w = f2bf(ot[dt][rg * 4 + 3] * inv);
            *(ushort4*)(Y + base + d0) = s4;
        }
}

// ---------------------------------------------------------------------------
extern "C" void kernel_launch(void* const* d_in, const int* in_sizes, int n_in,
                              void* d_out, int out_size, void* d_ws, size_t ws_size,
                              hipStream_t stream) {
    const float* x  = (const float*)d_in[0];
    const float* Wq = (const float*)d_in[1];
    const float* Wk = (const float*)d_in[2];
    const float* Wv = (const float*)d_in[3];
    const float* Wo = (const float*)d_in[4];

    unsigned short* ws = (unsigned short*)d_ws;
    const size_t nX = (size_t)Mc * Cc;   // 4194304
    const size_t nW = (size_t)Cc * Cc;   // 1048576
    size_t off = 0;
    unsigned short* xb  = ws + off; off += nX;
    unsigned short* Wqb = ws + off; off += nW;
    unsigned short* Wkb = ws + off; off += nW;
    unsigned short* Wvb = ws + off; off += nW;
    unsigned short* Wob = ws + off; off += nW;
    unsigned short* Qw  = ws + off; off += nX;
    unsigned short* Kw  = ws + off; off += nX;
    unsigned short* Vtw = ws + off; off += nX;
    unsigned short* Yb  = ws + off; off += nX;

    dim3 blk(256);
    cast_bf16<<<dim3((int)(nX / 8 / 256)), blk, 0, stream>>>(x, xb, (int)(nX / 8));
    cast_w4<<<dim3(512, 4), blk, 0, stream>>>(Wq, Wk, Wv, Wo, Wqb, Wkb, Wvb, Wob);

    dim3 gg(Mc / 128, Cc / 128);  // 32 x 8
    gemm_bt<0><<<gg, blk, 0, stream>>>(xb, Wqb, Qw);
    gemm_bt<0><<<gg, blk, 0, stream>>>(xb, Wkb, Kw);
    gemm_bt<1><<<gg, blk, 0, stream>>>(xb, Wvb, Vtw);

    dim3 ga(Tc / 128, Bc * Hc);   // 16 x 32
    attn_mfma<<<ga, blk, 0, stream>>>(Qw, Kw, Vtw, Yb);

    gemm_bt<3><<<gg, blk, 0, stream>>>(Yb, Wob, d_out);
}

// Round 4
// 121.373 us; speedup vs baseline: 11.1404x; 1.4168x over previous
//
#include <hip/hip_runtime.h>
#include <math.h>

typedef short bf16x8 __attribute__((ext_vector_type(8)));
typedef float f32x4 __attribute__((ext_vector_type(4)));
typedef float f32x16 __attribute__((ext_vector_type(16)));
typedef int int2v __attribute__((ext_vector_type(2)));

constexpr int Bc = 2, Tc = 2048, Cc = 1024, Hc = 16, Dc = 64;
constexpr int Mc = Bc * Tc;  // 4096

#if __has_builtin(__builtin_amdgcn_exp2f)
#define EXP2(x) __builtin_amdgcn_exp2f(x)
#else
#define EXP2(x) exp2f(x)
#endif

__device__ __forceinline__ unsigned short f2bf(float f) {
    union { float f; unsigned u; } v; v.f = f;
    unsigned r = v.u + 0x7fffu + ((v.u >> 16) & 1u);  // RNE
    return (unsigned short)(r >> 16);
}

__device__ __forceinline__ unsigned cvt_pk_bf16(float lo, float hi) {
    unsigned r;
    asm("v_cvt_pk_bf16_f32 %0, %1, %2" : "=v"(r) : "v"(lo), "v"(hi));
    return r;
}

__device__ __forceinline__ void gload16(const void* g, void* l) {
    __builtin_amdgcn_global_load_lds(
        (const __attribute__((address_space(1))) void*)g,
        (__attribute__((address_space(3))) void*)l, 16, 0, 0);
}

// ---------------------------------------------------------------------------
__global__ __launch_bounds__(256)
void cast_bf16(const float* __restrict__ in, unsigned short* __restrict__ out, int n8) {
    int i = blockIdx.x * 256 + threadIdx.x;
    if (i >= n8) return;
    const float4* p = (const float4*)in;
    float4 a = p[i * 2], b = p[i * 2 + 1];
    union { unsigned short u[8]; bf16x8 v; } r;
    r.u[0] = f2bf(a.x); r.u[1] = f2bf(a.y); r.u[2] = f2bf(a.z); r.u[3] = f2bf(a.w);
    r.u[4] = f2bf(b.x); r.u[5] = f2bf(b.y); r.u[6] = f2bf(b.z); r.u[7] = f2bf(b.w);
    *(bf16x8*)(out + i * 8) = r.v;
}

__global__ __launch_bounds__(256)
void cast_w4(const float* __restrict__ a, const float* __restrict__ b,
             const float* __restrict__ c, const float* __restrict__ d,
             unsigned short* __restrict__ oa, unsigned short* __restrict__ ob,
             unsigned short* __restrict__ oc, unsigned short* __restrict__ od) {
    const float* src = blockIdx.y == 0 ? a : blockIdx.y == 1 ? b : blockIdx.y == 2 ? c : d;
    unsigned short* dst = blockIdx.y == 0 ? oa : blockIdx.y == 1 ? ob : blockIdx.y == 2 ? oc : od;
    int i = blockIdx.x * 256 + threadIdx.x;
    const float4* p = (const float4*)src;
    float4 x = p[i * 2], y = p[i * 2 + 1];
    union { unsigned short u[8]; bf16x8 v; } r;
    r.u[0] = f2bf(x.x); r.u[1] = f2bf(x.y); r.u[2] = f2bf(x.z); r.u[3] = f2bf(x.w);
    r.u[4] = f2bf(y.x); r.u[5] = f2bf(y.y); r.u[6] = f2bf(y.z); r.u[7] = f2bf(y.w);
    *(bf16x8*)(dst + i * 8) = r.v;
}

// ---------------------------------------------------------------------------
// Fused QKV GEMM (NT), m97 structure: 128x128 tile, BK=32, 4 waves, 768 blocks.
// blockIdx.y: 0..7 -> Q (scaled by 0.125*log2e, scatter [B,H,T,D])
//             8..15 -> K (scatter [B,H,T,D]); 16..23 -> V (scatter [B,H,D,T]).
// ---------------------------------------------------------------------------
__global__ __launch_bounds__(256)
void gemm_qkv(const unsigned short* __restrict__ A,
              const unsigned short* __restrict__ Wq,
              const unsigned short* __restrict__ Wk,
              const unsigned short* __restrict__ Wv,
              unsigned short* __restrict__ Qo,
              unsigned short* __restrict__ Ko,
              unsigned short* __restrict__ Vo) {
    __shared__ unsigned short As[128 * 32];
    __shared__ unsigned short Bs[128 * 32];
    const int t = threadIdx.x;
    const int lane = t & 63, l15 = lane & 15, l4 = lane >> 4;
    const int w = t >> 6, wr = w >> 1, wc = w & 1;
    const int seg = blockIdx.y >> 3;              // 0=Q 1=K 2=V
    const unsigned short* W = seg == 0 ? Wq : seg == 1 ? Wk : Wv;
    const int m0 = blockIdx.x * 128, n0 = (blockIdx.y & 7) * 128;

    f32x4 acc[4][4] = {};

    for (int k0 = 0; k0 < Cc; k0 += 32) {
        __syncthreads();
        #pragma unroll
        for (int it = 0; it < 2; ++it) {
            int c = t + it * 256;
            int row = c >> 2, ko = (c & 3) << 3;
            gload16(A + (size_t)(m0 + row) * Cc + k0 + ko, As + c * 8);
            gload16(W + (size_t)(n0 + row) * Cc + k0 + ko, Bs + c * 8);
        }
        __syncthreads();
        bf16x8 af[4], bfr[4];
        #pragma unroll
        for (int i = 0; i < 4; ++i)
            af[i] = *(const bf16x8*)(As + ((wr * 64 + i * 16 + l15) * 32 + l4 * 8));
        #pragma unroll
        for (int j = 0; j < 4; ++j)
            bfr[j] = *(const bf16x8*)(Bs + ((wc * 64 + j * 16 + l15) * 32 + l4 * 8));
        #pragma unroll
        for (int i = 0; i < 4; ++i)
            #pragma unroll
            for (int j = 0; j < 4; ++j)
                acc[i][j] = __builtin_amdgcn_mfma_f32_16x16x32_bf16(af[i], bfr[j], acc[i][j], 0, 0, 0);
    }

    const float qscale = 0.18033688011112042f;  // 0.125 * log2(e)
    const int r0 = wr * 64 + (l4 << 2);
    const int c0 = wc * 64 + l15;
    #pragma unroll
    for (int i = 0; i < 4; ++i)
        #pragma unroll
        for (int j = 0; j < 4; ++j)
            #pragma unroll
            for (int r = 0; r < 4; ++r) {
                int row = m0 + r0 + i * 16 + r;
                int col = n0 + c0 + j * 16;
                float v = acc[i][j][r];
                int bb = row >> 11, tt = row & (Tc - 1);
                int hh = col >> 6, dd = col & 63;
                if (seg == 0)
                    Qo[((((size_t)bb * Hc + hh) * Tc + tt) << 6) + dd] = f2bf(v * qscale);
                else if (seg == 1)
                    Ko[((((size_t)bb * Hc + hh) * Tc + tt) << 6) + dd] = f2bf(v);
                else
                    Vo[(((size_t)bb * Hc + hh) * Dc + dd) * Tc + tt] = f2bf(v);
            }
}

// ---------------------------------------------------------------------------
// Out-projection GEMM (NT): 128x64 tile, 512 blocks (2/CU), fp32 out [M,C].
// ---------------------------------------------------------------------------
__global__ __launch_bounds__(256)
void gemm_out(const unsigned short* __restrict__ A,
              const unsigned short* __restrict__ W,
              float* __restrict__ outp) {
    __shared__ unsigned short As[128 * 32];
    __shared__ unsigned short Bs[64 * 32];
    const int t = threadIdx.x;
    const int lane = t & 63, l15 = lane & 15, l4 = lane >> 4;
    const int w = t >> 6, wr = w >> 1, wc = w & 1;
    const int m0 = blockIdx.x * 128, n0 = blockIdx.y * 64;

    f32x4 acc[4][2] = {};

    for (int k0 = 0; k0 < Cc; k0 += 32) {
        __syncthreads();
        #pragma unroll
        for (int it = 0; it < 2; ++it) {
            int c = t + it * 256;
            int row = c >> 2, ko = (c & 3) << 3;
            gload16(A + (size_t)(m0 + row) * Cc + k0 + ko, As + c * 8);
        }
        {
            int c = t;
            int row = c >> 2, ko = (c & 3) << 3;
            gload16(W + (size_t)(n0 + row) * Cc + k0 + ko, Bs + c * 8);
        }
        __syncthreads();
        bf16x8 af[4], bfr[2];
        #pragma unroll
        for (int i = 0; i < 4; ++i)
            af[i] = *(const bf16x8*)(As + ((wr * 64 + i * 16 + l15) * 32 + l4 * 8));
        #pragma unroll
        for (int j = 0; j < 2; ++j)
            bfr[j] = *(const bf16x8*)(Bs + ((wc * 32 + j * 16 + l15) * 32 + l4 * 8));
        #pragma unroll
        for (int i = 0; i < 4; ++i)
            #pragma unroll
            for (int j = 0; j < 2; ++j)
                acc[i][j] = __builtin_amdgcn_mfma_f32_16x16x32_bf16(af[i], bfr[j], acc[i][j], 0, 0, 0);
    }

    const int r0 = wr * 64 + (l4 << 2);
    const int c0 = wc * 32 + l15;
    #pragma unroll
    for (int i = 0; i < 4; ++i)
        #pragma unroll
        for (int j = 0; j < 2; ++j)
            #pragma unroll
            for (int r = 0; r < 4; ++r)
                outp[(size_t)(m0 + r0 + i * 16 + r) * Cc + n0 + c0 + j * 16] = acc[i][j][r];
}

// ---------------------------------------------------------------------------
// MFMA causal flash attention, swapped-operand 32x32x16, exp2-domain softmax
// (Q pre-scaled by 0.125*log2e), defer-max (T13), double-buffered K/V LDS.
// Grid: x = bh (32)  -> XCD-local per head; y = 16, qb = 15 - y (heavy first).
// ---------------------------------------------------------------------------
__global__ __launch_bounds__(256)
void attn_mfma(const unsigned short* __restrict__ Q,
               const unsigned short* __restrict__ K,
               const unsigned short* __restrict__ Vt,
               unsigned short* __restrict__ Y) {
    __shared__ unsigned short Ks[2][64 * 64];  // [buf][key][d]   (swizzled)
    __shared__ unsigned short Vs[2][64 * 64];  // [buf][d][key]   (swizzled)

    const int t = threadIdx.x, lane = t & 63, w = t >> 6;
    const int l31 = lane & 31, h = lane >> 5;
    const int qb = (int)gridDim.y - 1 - blockIdx.y;   // heavy blocks first
    const int bh = blockIdx.x;
    const int bb = bh >> 4, hh = bh & 15;
    const int qbase = qb * 128 + w * 32;
    const int q = qbase + l31;

    const unsigned short* Qp = Q + (size_t)bh * Tc * Dc;
    const unsigned short* Kp = K + (size_t)bh * Tc * Dc;
    const unsigned short* Vp = Vt + (size_t)bh * Dc * Tc;

    // Q as B-operand: col=q=lane&31, k = kc*16 + h*8 + j  (pre-scaled)
    bf16x8 qf[4];
    #pragma unroll
    for (int kc = 0; kc < 4; ++kc)
        qf[kc] = *(const bf16x8*)(Qp + (size_t)q * 64 + kc * 16 + h * 8);

    f32x16 ot[2] = {};          // O^T: rows d=dt*32+(r&3)+8*(r>>2)+4h, col q
    float m = -INFINITY, lsum = 0.f;

    auto stage = [&](int kb, int buf) {
        #pragma unroll
        for (int it = 0; it < 2; ++it) {
            int c = t + it * 256;
            int row = c >> 3, slot = c & 7;
            int ss = slot ^ (row & 7);  // pre-swizzled source
            gload16(Kp + (size_t)(kb * 64 + row) * 64 + ss * 8, &Ks[buf][c * 8]);
            gload16(Vp + (size_t)row * Tc + kb * 64 + ss * 8, &Vs[buf][c * 8]);
        }
    };

    const int nkb = 2 * qb + 2;
    stage(0, 0);
    __syncthreads();

    for (int kb = 0; kb < nkb; ++kb) {
        const int cur = kb & 1;
        if (kb + 1 < nkb) stage(kb + 1, cur ^ 1);  // prefetch overlaps compute

        if (kb * 64 <= qbase + 31) {
            // ---- S^T = K @ Q^T  (log2 domain; 2 key-tiles of 32) ----
            f32x16 st[2] = {};
            #pragma unroll
            for (int nt = 0; nt < 2; ++nt) {
                int key = nt * 32 + l31;
                #pragma unroll
                for (int kc = 0; kc < 4; ++kc) {
                    int boff = (kc * 32 + h * 16) ^ ((key & 7) << 4);
                    bf16x8 kf = *(const bf16x8*)(&Ks[cur][((key << 7) + boff) >> 1]);
                    st[nt] = __builtin_amdgcn_mfma_f32_32x32x16_bf16(kf, qf[kc], st[nt], 0, 0, 0);
                }
            }

            if (kb * 64 + 63 > qbase) {  // causal mask (diagonal tiles only)
                #pragma unroll
                for (int nt = 0; nt < 2; ++nt)
                    #pragma unroll
                    for (int r = 0; r < 16; ++r) {
                        int key = kb * 64 + nt * 32 + (r & 3) + 8 * (r >> 2) + 4 * h;
                        if (key > q) st[nt][r] = -1e30f;
                    }
            }

            // ---- lane-local row max ----
            float mx[16];
            #pragma unroll
            for (int r = 0; r < 16; ++r) mx[r] = fmaxf(st[0][r], st[1][r]);
            #pragma unroll
            for (int s2 = 8; s2 > 0; s2 >>= 1)
                #pragma unroll
                for (int r = 0; r < s2; ++r) mx[r] = fmaxf(mx[r], mx[r + s2]);
            float tmax = fmaxf(mx[0], __shfl_xor(mx[0], 32));

            // ---- defer-max: rescale only when the max really grew ----
            if (__any(tmax > m + 8.f)) {
                float mn = fmaxf(m, tmax);
                float al = EXP2(m - mn);
                m = mn;
                lsum *= al;
                #pragma unroll
                for (int dt = 0; dt < 2; ++dt)
                    #pragma unroll
                    for (int r = 0; r < 16; ++r) ot[dt][r] *= al;
            }

            float ps = 0.f;
            #pragma unroll
            for (int nt = 0; nt < 2; ++nt)
                #pragma unroll
                for (int r = 0; r < 16; ++r) {
                    float p = EXP2(st[nt][r] - m);
                    st[nt][r] = p;
                    ps += p;
                }
            lsum += ps;

            // ---- P^T -> bf16 B-frags in-register (T12), then PV ----
            #pragma unroll
            for (int nt = 0; nt < 2; ++nt) {
                unsigned a0 = cvt_pk_bf16(st[nt][0],  st[nt][1]);
                unsigned b0 = cvt_pk_bf16(st[nt][4],  st[nt][5]);
                unsigned a1 = cvt_pk_bf16(st[nt][2],  st[nt][3]);
                unsigned b1 = cvt_pk_bf16(st[nt][6],  st[nt][7]);
                int2v r0 = __builtin_amdgcn_permlane32_swap((int)a0, (int)b0, false, false);
                int2v r1 = __builtin_amdgcn_permlane32_swap((int)a1, (int)b1, false, false);
                union { unsigned u[4]; bf16x8 v; } pf0, pf1;
                pf0.u[0] = r0.x; pf0.u[1] = r1.x; pf0.u[2] = r0.y; pf0.u[3] = r1.y;
                unsigned c0 = cvt_pk_bf16(st[nt][8],  st[nt][9]);
                unsigned d0 = cvt_pk_bf16(st[nt][12], st[nt][13]);
                unsigned c1 = cvt_pk_bf16(st[nt][10], st[nt][11]);
                unsigned d1 = cvt_pk_bf16(st[nt][14], st[nt][15]);
                int2v r2 = __builtin_amdgcn_permlane32_swap((int)c0, (int)d0, false, false);
                int2v r3 = __builtin_amdgcn_permlane32_swap((int)c1, (int)d1, false, false);
                pf1.u[0] = r2.x; pf1.u[1] = r3.x; pf1.u[2] = r2.y; pf1.u[3] = r3.y;

                #pragma unroll
                for (int dt = 0; dt < 2; ++dt) {
                    int d = dt * 32 + l31;
                    int v0off = (nt * 64 + h * 16) ^ ((d & 7) << 4);
                    bf16x8 vf0 = *(const bf16x8*)(&Vs[cur][((d << 7) + v0off) >> 1]);
                    ot[dt] = __builtin_amdgcn_mfma_f32_32x32x16_bf16(vf0, pf0.v, ot[dt], 0, 0, 0);
                }
                #pragma unroll
                for (int dt = 0; dt < 2; ++dt) {
                    int d = dt * 32 + l31;
                    int v1off = (nt * 64 + 32 + h * 16) ^ ((d & 7) << 4);
                    bf16x8 vf1 = *(const bf16x8*)(&Vs[cur][((d << 7) + v1off) >> 1]);
                    ot[dt] = __builtin_amdgcn_mfma_f32_32x32x16_bf16(vf1, pf1.v, ot[dt], 0, 0, 0);
                }
            }
        }
        __syncthreads();  // drains prefetch + publishes buffers
    }

    // ---- epilogue ----
    float lf = lsum + __shfl_xor(lsum, 32);
    float inv = 1.f / lf;
    size_t base = ((size_t)bb * Tc + q) * Cc + hh * 64;
    #pragma unroll
    for (int dt = 0; dt < 2; ++dt)
        #pragma unroll
        for (int rg = 0; rg < 4; ++rg) {
            int d0 = dt * 32 + rg * 8 + 4 * h;
            ushort4 s4;
            s4.x = f2bf(ot[dt][rg * 4 + 0] * inv);
            s4.y = f2bf(ot[dt][rg * 4 + 1] * inv);
            s4.z = f2bf(ot[dt][rg * 4 + 2] * inv);
            s4.w = f2bf(ot[dt][rg * 4 + 3] * inv);
            *(ushort4*)(Y + base + d0) = s4;
        }
}

// ---------------------------------------------------------------------------
extern "C" void kernel_launch(void* const* d_in, const int* in_sizes, int n_in,
                              void* d_out, int out_size, void* d_ws, size_t ws_size,
                              hipStream_t stream) {
    const float* x  = (const float*)d_in[0];
    const float* Wq = (const float*)d_in[1];
    const float* Wk = (const float*)d_in[2];
    const float* Wv = (const float*)d_in[3];
    const float* Wo = (const float*)d_in[4];

    unsigned short* ws = (unsigned short*)d_ws;
    const size_t nX = (size_t)Mc * Cc;   // 4194304
    const size_t nW = (size_t)Cc * Cc;   // 1048576
    size_t off = 0;
    unsigned short* xb  = ws + off; off += nX;
    unsigned short* Wqb = ws + off; off += nW;
    unsigned short* Wkb = ws + off; off += nW;
    unsigned short* Wvb = ws + off; off += nW;
    unsigned short* Wob = ws + off; off += nW;
    unsigned short* Qw  = ws + off; off += nX;
    unsigned short* Kw  = ws + off; off += nX;
    unsigned short* Vtw = ws + off; off += nX;
    unsigned short* Yb  = ws + off; off += nX;

    dim3 blk(256);
    cast_bf16<<<dim3((int)(nX / 8 / 256)), blk, 0, stream>>>(x, xb, (int)(nX / 8));
    cast_w4<<<dim3(512, 4), blk, 0, stream>>>(Wq, Wk, Wv, Wo, Wqb, Wkb, Wvb, Wob);

    gemm_qkv<<<dim3(Mc / 128, 24), blk, 0, stream>>>(xb, Wqb, Wkb, Wvb, Qw, Kw, Vtw);

    attn_mfma<<<dim3(Bc * Hc, Tc / 128), blk, 0, stream>>>(Qw, Kw, Vtw, Yb);

    gemm_out<<<dim3(Mc / 128, Cc / 64), blk, 0, stream>>>(Yb, Wob, (float*)d_out);
}

// Round 5
// 117.874 us; speedup vs baseline: 11.4711x; 1.0297x over previous
//
#include <hip/hip_runtime.h>
#include <math.h>

typedef short bf16x8 __attribute__((ext_vector_type(8)));
typedef float f32x4 __attribute__((ext_vector_type(4)));
typedef float f32x16 __attribute__((ext_vector_type(16)));
typedef int int2v __attribute__((ext_vector_type(2)));

constexpr int Bc = 2, Tc = 2048, Cc = 1024, Hc = 16, Dc = 64;
constexpr int Mc = Bc * Tc;  // 4096

#if __has_builtin(__builtin_amdgcn_exp2f)
#define EXP2(x) __builtin_amdgcn_exp2f(x)
#else
#define EXP2(x) exp2f(x)
#endif

__device__ __forceinline__ unsigned short f2bf(float f) {
    union { float f; unsigned u; } v; v.f = f;
    unsigned r = v.u + 0x7fffu + ((v.u >> 16) & 1u);  // RNE
    return (unsigned short)(r >> 16);
}

__device__ __forceinline__ float bf2f(unsigned short u) {
    union { unsigned u; float f; } v; v.u = (unsigned)u << 16; return v.f;
}

__device__ __forceinline__ unsigned cvt_pk_bf16(float lo, float hi) {
    unsigned r;
    asm("v_cvt_pk_bf16_f32 %0, %1, %2" : "=v"(r) : "v"(lo), "v"(hi));
    return r;
}

__device__ __forceinline__ void gload16(const void* g, void* l) {
    __builtin_amdgcn_global_load_lds(
        (const __attribute__((address_space(1))) void*)g,
        (__attribute__((address_space(3))) void*)l, 16, 0, 0);
}

// ---------------------------------------------------------------------------
__global__ __launch_bounds__(256)
void cast_bf16(const float* __restrict__ in, unsigned short* __restrict__ out, int n8) {
    int i = blockIdx.x * 256 + threadIdx.x;
    if (i >= n8) return;
    const float4* p = (const float4*)in;
    float4 a = p[i * 2], b = p[i * 2 + 1];
    union { unsigned short u[8]; bf16x8 v; } r;
    r.u[0] = f2bf(a.x); r.u[1] = f2bf(a.y); r.u[2] = f2bf(a.z); r.u[3] = f2bf(a.w);
    r.u[4] = f2bf(b.x); r.u[5] = f2bf(b.y); r.u[6] = f2bf(b.z); r.u[7] = f2bf(b.w);
    *(bf16x8*)(out + i * 8) = r.v;
}

__global__ __launch_bounds__(256)
void cast_w4(const float* __restrict__ a, const float* __restrict__ b,
             const float* __restrict__ c, const float* __restrict__ d,
             unsigned short* __restrict__ oa, unsigned short* __restrict__ ob,
             unsigned short* __restrict__ oc, unsigned short* __restrict__ od) {
    const float* src = blockIdx.y == 0 ? a : blockIdx.y == 1 ? b : blockIdx.y == 2 ? c : d;
    unsigned short* dst = blockIdx.y == 0 ? oa : blockIdx.y == 1 ? ob : blockIdx.y == 2 ? oc : od;
    int i = blockIdx.x * 256 + threadIdx.x;
    const float4* p = (const float4*)src;
    float4 x = p[i * 2], y = p[i * 2 + 1];
    union { unsigned short u[8]; bf16x8 v; } r;
    r.u[0] = f2bf(x.x); r.u[1] = f2bf(x.y); r.u[2] = f2bf(x.z); r.u[3] = f2bf(x.w);
    r.u[4] = f2bf(y.x); r.u[5] = f2bf(y.y); r.u[6] = f2bf(y.z); r.u[7] = f2bf(y.w);
    *(bf16x8*)(dst + i * 8) = r.v;
}

// ---------------------------------------------------------------------------
// Fused QKV GEMM (NT), m97 structure: 128x128 tile, BK=32, 4 waves, 768 blocks.
// ---------------------------------------------------------------------------
__global__ __launch_bounds__(256)
void gemm_qkv(const unsigned short* __restrict__ A,
              const unsigned short* __restrict__ Wq,
              const unsigned short* __restrict__ Wk,
              const unsigned short* __restrict__ Wv,
              unsigned short* __restrict__ Qo,
              unsigned short* __restrict__ Ko,
              unsigned short* __restrict__ Vo) {
    __shared__ unsigned short As[128 * 32];
    __shared__ unsigned short Bs[128 * 32];
    const int t = threadIdx.x;
    const int lane = t & 63, l15 = lane & 15, l4 = lane >> 4;
    const int w = t >> 6, wr = w >> 1, wc = w & 1;
    const int seg = blockIdx.y >> 3;              // 0=Q 1=K 2=V
    const unsigned short* W = seg == 0 ? Wq : seg == 1 ? Wk : Wv;
    const int m0 = blockIdx.x * 128, n0 = (blockIdx.y & 7) * 128;

    f32x4 acc[4][4] = {};

    for (int k0 = 0; k0 < Cc; k0 += 32) {
        __syncthreads();
        #pragma unroll
        for (int it = 0; it < 2; ++it) {
            int c = t + it * 256;
            int row = c >> 2, ko = (c & 3) << 3;
            gload16(A + (size_t)(m0 + row) * Cc + k0 + ko, As + c * 8);
            gload16(W + (size_t)(n0 + row) * Cc + k0 + ko, Bs + c * 8);
        }
        __syncthreads();
        bf16x8 af[4], bfr[4];
        #pragma unroll
        for (int i = 0; i < 4; ++i)
            af[i] = *(const bf16x8*)(As + ((wr * 64 + i * 16 + l15) * 32 + l4 * 8));
        #pragma unroll
        for (int j = 0; j < 4; ++j)
            bfr[j] = *(const bf16x8*)(Bs + ((wc * 64 + j * 16 + l15) * 32 + l4 * 8));
        #pragma unroll
        for (int i = 0; i < 4; ++i)
            #pragma unroll
            for (int j = 0; j < 4; ++j)
                acc[i][j] = __builtin_amdgcn_mfma_f32_16x16x32_bf16(af[i], bfr[j], acc[i][j], 0, 0, 0);
    }

    const float qscale = 0.18033688011112042f;  // 0.125 * log2(e)
    const int r0 = wr * 64 + (l4 << 2);
    const int c0 = wc * 64 + l15;
    #pragma unroll
    for (int i = 0; i < 4; ++i)
        #pragma unroll
        for (int j = 0; j < 4; ++j)
            #pragma unroll
            for (int r = 0; r < 4; ++r) {
                int row = m0 + r0 + i * 16 + r;
                int col = n0 + c0 + j * 16;
                float v = acc[i][j][r];
                int bb = row >> 11, tt = row & (Tc - 1);
                int hh = col >> 6, dd = col & 63;
                if (seg == 0)
                    Qo[((((size_t)bb * Hc + hh) * Tc + tt) << 6) + dd] = f2bf(v * qscale);
                else if (seg == 1)
                    Ko[((((size_t)bb * Hc + hh) * Tc + tt) << 6) + dd] = f2bf(v);
                else
                    Vo[(((size_t)bb * Hc + hh) * Dc + dd) * Tc + tt] = f2bf(v);
            }
}

// ---------------------------------------------------------------------------
// Out-projection GEMM (NT): 128x64 tile, 512 blocks, fp32 out [M,C].
// ---------------------------------------------------------------------------
__global__ __launch_bounds__(256)
void gemm_out(const unsigned short* __restrict__ A,
              const unsigned short* __restrict__ W,
              float* __restrict__ outp) {
    __shared__ unsigned short As[128 * 32];
    __shared__ unsigned short Bs[64 * 32];
    const int t = threadIdx.x;
    const int lane = t & 63, l15 = lane & 15, l4 = lane >> 4;
    const int w = t >> 6, wr = w >> 1, wc = w & 1;
    const int m0 = blockIdx.x * 128, n0 = blockIdx.y * 64;

    f32x4 acc[4][2] = {};

    for (int k0 = 0; k0 < Cc; k0 += 32) {
        __syncthreads();
        #pragma unroll
        for (int it = 0; it < 2; ++it) {
            int c = t + it * 256;
            int row = c >> 2, ko = (c & 3) << 3;
            gload16(A + (size_t)(m0 + row) * Cc + k0 + ko, As + c * 8);
        }
        {
            int c = t;
            int row = c >> 2, ko = (c & 3) << 3;
            gload16(W + (size_t)(n0 + row) * Cc + k0 + ko, Bs + c * 8);
        }
        __syncthreads();
        bf16x8 af[4], bfr[2];
        #pragma unroll
        for (int i = 0; i < 4; ++i)
            af[i] = *(const bf16x8*)(As + ((wr * 64 + i * 16 + l15) * 32 + l4 * 8));
        #pragma unroll
        for (int j = 0; j < 2; ++j)
            bfr[j] = *(const bf16x8*)(Bs + ((wc * 32 + j * 16 + l15) * 32 + l4 * 8));
        #pragma unroll
        for (int i = 0; i < 4; ++i)
            #pragma unroll
            for (int j = 0; j < 2; ++j)
                acc[i][j] = __builtin_amdgcn_mfma_f32_16x16x32_bf16(af[i], bfr[j], acc[i][j], 0, 0, 0);
    }

    const int r0 = wr * 64 + (l4 << 2);
    const int c0 = wc * 32 + l15;
    #pragma unroll
    for (int i = 0; i < 4; ++i)
        #pragma unroll
        for (int j = 0; j < 2; ++j)
            #pragma unroll
            for (int r = 0; r < 4; ++r)
                outp[(size_t)(m0 + r0 + i * 16 + r) * Cc + n0 + c0 + j * 16] = acc[i][j][r];
}

// ---------------------------------------------------------------------------
// MFMA causal flash attention with split-K (flash-decoding) for heavy chunks.
// 64 q-rows per block (2 waves x 32). Chunks c>=16 are split into two K-halves
// handled by separate blocks producing unnormalized partials + (m,l); chunks
// c<16 write final output directly. Dispatch order = LPT (duration desc).
// Job encoding: bit7 = split, bit6 = half, bits4..0 = chunk c.
// ---------------------------------------------------------------------------
__device__ __constant__ unsigned char JOBS[48] = {
    159, 223, 222, 15, 158, 157, 221, 220, 14, 156,
    155, 219, 218, 13, 154, 153, 217, 216, 12, 152,
    151, 215, 214, 11, 150, 149, 213, 212, 10, 148,
    147, 211, 210,  9, 146, 145, 209, 208,  8, 144,
      7,   6,   5,  4,   3,   2,   1,   0
};

__global__ __launch_bounds__(128)
void attn_mfma(const unsigned short* __restrict__ Q,
               const unsigned short* __restrict__ K,
               const unsigned short* __restrict__ Vt,
               unsigned short* __restrict__ Y,
               unsigned short* __restrict__ P1,   // half1 partial O (bf16, [B,T,C] layout)
               float* __restrict__ mlf) {         // m0[32768], l0, m1, l1
    __shared__ unsigned short Ks[2][64 * 64];  // [buf][key][d]   (swizzled)
    __shared__ unsigned short Vs[2][64 * 64];  // [buf][d][key]   (swizzled)

    const int t = threadIdx.x, lane = t & 63, w = t >> 6;
    const int l31 = lane & 31, h = lane >> 5;
    const int bh = blockIdx.x;
    const int bb = bh >> 4, hh = bh & 15;

    const unsigned char job = JOBS[blockIdx.y];
    const int c = job & 31;
    const bool split = job & 128;
    const int half = (job >> 6) & 1;
    const int ntile = c + 1, smid = ntile >> 1;
    const int kb0 = (split && half) ? smid : 0;
    const int kb1 = (split && !half) ? smid : ntile;

    const int qbase = c * 64 + w * 32;
    const int q = qbase + l31;

    const unsigned short* Qp = Q + (size_t)bh * Tc * Dc;
    const unsigned short* Kp = K + (size_t)bh * Tc * Dc;
    const unsigned short* Vp = Vt + (size_t)bh * Dc * Tc;

    // Q as B-operand: col=q=lane&31, k = kc*16 + h*8 + j  (pre-scaled by 0.125*log2e)
    bf16x8 qf[4];
    #pragma unroll
    for (int kc = 0; kc < 4; ++kc)
        qf[kc] = *(const bf16x8*)(Qp + (size_t)q * 64 + kc * 16 + h * 8);

    f32x16 ot[2] = {};          // O^T: rows d=dt*32+(r&3)+8*(r>>2)+4h, col q
    float m = -INFINITY, lsum = 0.f;

    auto stage = [&](int kb, int buf) {
        #pragma unroll
        for (int it = 0; it < 4; ++it) {
            int idx = t + it * 128;
            int row = idx >> 3, slot = idx & 7;
            int ss = slot ^ (row & 7);  // pre-swizzled source
            gload16(Kp + (size_t)(kb * 64 + row) * 64 + ss * 8, &Ks[buf][idx * 8]);
            gload16(Vp + (size_t)row * Tc + kb * 64 + ss * 8, &Vs[buf][idx * 8]);
        }
    };

    stage(kb0, 0);
    __syncthreads();

    for (int kb = kb0; kb < kb1; ++kb) {
        const int cur = (kb - kb0) & 1;
        if (kb + 1 < kb1) stage(kb + 1, cur ^ 1);  // prefetch overlaps compute

        // ---- S^T = K @ Q^T  (log2 domain; 2 key-tiles of 32) ----
        f32x16 st[2] = {};
        __builtin_amdgcn_s_setprio(1);
        #pragma unroll
        for (int nt = 0; nt < 2; ++nt) {
            int key = nt * 32 + l31;
            #pragma unroll
            for (int kc = 0; kc < 4; ++kc) {
                int boff = (kc * 32 + h * 16) ^ ((key & 7) << 4);
                bf16x8 kf = *(const bf16x8*)(&Ks[cur][((key << 7) + boff) >> 1]);
                st[nt] = __builtin_amdgcn_mfma_f32_32x32x16_bf16(kf, qf[kc], st[nt], 0, 0, 0);
            }
        }
        __builtin_amdgcn_s_setprio(0);

        if (kb * 64 + 63 > qbase) {  // causal mask (diagonal tile only)
            #pragma unroll
            for (int nt = 0; nt < 2; ++nt)
                #pragma unroll
                for (int r = 0; r < 16; ++r) {
                    int key = kb * 64 + nt * 32 + (r & 3) + 8 * (r >> 2) + 4 * h;
                    if (key > q) st[nt][r] = -1e30f;
                }
        }

        // ---- lane-local row max ----
        float mx[16];
        #pragma unroll
        for (int r = 0; r < 16; ++r) mx[r] = fmaxf(st[0][r], st[1][r]);
        #pragma unroll
        for (int s2 = 8; s2 > 0; s2 >>= 1)
            #pragma unroll
            for (int r = 0; r < s2; ++r) mx[r] = fmaxf(mx[r], mx[r + s2]);
        float tmax = fmaxf(mx[0], __shfl_xor(mx[0], 32));

        // ---- defer-max (T13): rescale only when the max really grew ----
        if (__any(tmax > m + 8.f)) {
            float mn = fmaxf(m, tmax);
            float al = EXP2(m - mn);
            m = mn;
            lsum *= al;
            #pragma unroll
            for (int dt = 0; dt < 2; ++dt)
                #pragma unroll
                for (int r = 0; r < 16; ++r) ot[dt][r] *= al;
        }

        float psa[4] = {0.f, 0.f, 0.f, 0.f};
        #pragma unroll
        for (int nt = 0; nt < 2; ++nt)
            #pragma unroll
            for (int r = 0; r < 16; ++r) {
                float p = EXP2(st[nt][r] - m);
                st[nt][r] = p;
                psa[r & 3] += p;
            }
        lsum += (psa[0] + psa[1]) + (psa[2] + psa[3]);

        // ---- P^T -> bf16 B-frags in-register (T12), then PV ----
        #pragma unroll
        for (int nt = 0; nt < 2; ++nt) {
            unsigned a0 = cvt_pk_bf16(st[nt][0],  st[nt][1]);
            unsigned b0 = cvt_pk_bf16(st[nt][4],  st[nt][5]);
            unsigned a1 = cvt_pk_bf16(st[nt][2],  st[nt][3]);
            unsigned b1 = cvt_pk_bf16(st[nt][6],  st[nt][7]);
            int2v r0 = __builtin_amdgcn_permlane32_swap((int)a0, (int)b0, false, false);
            int2v r1 = __builtin_amdgcn_permlane32_swap((int)a1, (int)b1, false, false);
            union { unsigned u[4]; bf16x8 v; } pf0, pf1;
            pf0.u[0] = r0.x; pf0.u[1] = r1.x; pf0.u[2] = r0.y; pf0.u[3] = r1.y;
            unsigned c0 = cvt_pk_bf16(st[nt][8],  st[nt][9]);
            unsigned d0 = cvt_pk_bf16(st[nt][12], st[nt][13]);
            unsigned c1 = cvt_pk_bf16(st[nt][10], st[nt][11]);
            unsigned d1 = cvt_pk_bf16(st[nt][14], st[nt][15]);
            int2v r2 = __builtin_amdgcn_permlane32_swap((int)c0, (int)d0, false, false);
            int2v r3 = __builtin_amdgcn_permlane32_swap((int)c1, (int)d1, false, false);
            pf1.u[0] = r2.x; pf1.u[1] = r3.x; pf1.u[2] = r2.y; pf1.u[3] = r3.y;

            __builtin_amdgcn_s_setprio(1);
            #pragma unroll
            for (int dt = 0; dt < 2; ++dt) {
                int d = dt * 32 + l31;
                int v0off = (nt * 64 + h * 16) ^ ((d & 7) << 4);
                bf16x8 vf0 = *(const bf16x8*)(&Vs[cur][((d << 7) + v0off) >> 1]);
                ot[dt] = __builtin_amdgcn_mfma_f32_32x32x16_bf16(vf0, pf0.v, ot[dt], 0, 0, 0);
            }
            #pragma unroll
            for (int dt = 0; dt < 2; ++dt) {
                int d = dt * 32 + l31;
                int v1off = (nt * 64 + 32 + h * 16) ^ ((d & 7) << 4);
                bf16x8 vf1 = *(const bf16x8*)(&Vs[cur][((d << 7) + v1off) >> 1]);
                ot[dt] = __builtin_amdgcn_mfma_f32_32x32x16_bf16(vf1, pf1.v, ot[dt], 0, 0, 0);
            }
            __builtin_amdgcn_s_setprio(0);
        }
        __syncthreads();  // drains prefetch + publishes buffers
    }

    // ---- epilogue ----
    float lf = lsum + __shfl_xor(lsum, 32);
    unsigned short* dst = (split && half) ? P1 : Y;
    float inv = split ? 1.f : 1.f / lf;
    size_t base = ((size_t)bb * Tc + q) * Cc + hh * 64;
    #pragma unroll
    for (int dt = 0; dt < 2; ++dt)
        #pragma unroll
        for (int rg = 0; rg < 4; ++rg) {
            int d0 = dt * 32 + rg * 8 + 4 * h;
            ushort4 s4;
            s4.x = f2bf(ot[dt][rg * 4 + 0] * inv);
            s4.y = f2bf(ot[dt][rg * 4 + 1] * inv);
            s4.z = f2bf(ot[dt][rg * 4 + 2] * inv);
            s4.w = f2bf(ot[dt][rg * 4 + 3] * inv);
            *(ushort4*)(dst + base + d0) = s4;
        }
    if (split && h == 0) {
        int ridx = bh * 1024 + (q - 1024);
        mlf[ridx + (half ? 65536 : 0)]          = m;   // m
        mlf[ridx + (half ? 98304 : 32768)]      = lf;  // l
    }
}

// ---------------------------------------------------------------------------
// Combine the two K-halves for rows q in [1024, 2048).
// ---------------------------------------------------------------------------
__global__ __launch_bounds__(256)
void attn_combine(unsigned short* __restrict__ Y,
                  const unsigned short* __restrict__ P1,
                  const float* __restrict__ mlf) {
    int tid = blockIdx.x * 256 + threadIdx.x;   // 0 .. 262143
    int ridx = tid >> 3;                         // 0 .. 32767
    int d0 = (tid & 7) * 8;
    int bh = ridx >> 10, qq = ridx & 1023;
    int bb = bh >> 4, hh = bh & 15;
    int q = 1024 + qq;
    size_t off = ((size_t)bb * Tc + q) * Cc + hh * 64 + d0;
    float m0 = mlf[ridx], l0 = mlf[ridx + 32768];
    float m1 = mlf[ridx + 65536], l1 = mlf[ridx + 98304];
    float M = fmaxf(m0, m1);
    float a0 = exp2f(m0 - M), a1 = exp2f(m1 - M);
    float inv = 1.f / (l0 * a0 + l1 * a1);
    union { unsigned short u[8]; bf16x8 v; } y0, y1, r;
    y0.v = *(const bf16x8*)(Y + off);
    y1.v = *(const bf16x8*)(P1 + off);
    #pragma unroll
    for (int j = 0; j < 8; ++j)
        r.u[j] = f2bf((bf2f(y0.u[j]) * a0 + bf2f(y1.u[j]) * a1) * inv);
    *(bf16x8*)(Y + off) = r.v;
}

// ---------------------------------------------------------------------------
extern "C" void kernel_launch(void* const* d_in, const int* in_sizes, int n_in,
                              void* d_out, int out_size, void* d_ws, size_t ws_size,
                              hipStream_t stream) {
    const float* x  = (const float*)d_in[0];
    const float* Wq = (const float*)d_in[1];
    const float* Wk = (const float*)d_in[2];
    const float* Wv = (const float*)d_in[3];
    const float* Wo = (const float*)d_in[4];

    unsigned short* ws = (unsigned short*)d_ws;
    const size_t nX = (size_t)Mc * Cc;   // 4194304
    const size_t nW = (size_t)Cc * Cc;   // 1048576
    size_t off = 0;
    unsigned short* xb  = ws + off; off += nX;   // dead after gemm_qkv -> P1 partial
    unsigned short* Wqb = ws + off; off += nW;   // dead after gemm_qkv -> ml buffer
    unsigned short* Wkb = ws + off; off += nW;
    unsigned short* Wvb = ws + off; off += nW;
    unsigned short* Wob = ws + off; off += nW;
    unsigned short* Qw  = ws + off; off += nX;
    unsigned short* Kw  = ws + off; off += nX;
    unsigned short* Vtw = ws + off; off += nX;
    unsigned short* Yb  = ws + off; off += nX;

    dim3 blk(256);
    cast_bf16<<<dim3((int)(nX / 8 / 256)), blk, 0, stream>>>(x, xb, (int)(nX / 8));
    cast_w4<<<dim3(512, 4), blk, 0, stream>>>(Wq, Wk, Wv, Wo, Wqb, Wkb, Wvb, Wob);

    gemm_qkv<<<dim3(Mc / 128, 24), blk, 0, stream>>>(xb, Wqb, Wkb, Wvb, Qw, Kw, Vtw);

    // xb and Wqb are dead now; reuse as split-K partial buffers.
    unsigned short* P1 = xb;
    float* mlf = (float*)Wqb;
    attn_mfma<<<dim3(Bc * Hc, 48), dim3(128), 0, stream>>>(Qw, Kw, Vtw, Yb, P1, mlf);
    attn_combine<<<dim3(1024), blk, 0, stream>>>(Yb, P1, mlf);

    gemm_out<<<dim3(Mc / 128, Cc / 64), blk, 0, stream>>>(Yb, Wob, (float*)d_out);
}